// Round 6
// baseline (1595.315 us; speedup 1.0000x reference)
//
#include <hip/hip_runtime.h>
#include <math.h>

// ---------------------------------------------------------------------------
// HFPS: CNN (4 residual blocks, circular 3x3 conv, 48x48, 64ch) ->
//       A = [[Fvv[n][:,n], Fvh_n],[-Fvh_n^T, Fhh_a]] (1048x1048 skew) ->
//       sign(Pf(A)), log|Pf(A)| + log_J
// Pfaffian via unpivoted blocked skew LDL^T with 2x2 pivots, fp64.
//   Pf = prod(t_p); log|Pf| = sum log|t_p| = 0.5*slogdet(A).
//
// R6 changes (R5 post-mortem: fence-free coherent atomics WIN 3086->1070 us;
// remaining limit = ~100 KB in flight device-wide: phase-T per-tile
// sync-drains serialize one memory round trip at a time, and full-square
// maintenance doubles traffic):
//   - Phase T: 64x64 tiles, LOWER TRIANGLE ONLY (skew symmetry halves
//     traffic+flops), batched stage+acc loads (~96 KB in flight per item),
//     1 sync before compute, 1 store burst per item.
//   - Phase R: lane-per-column-pair + __shfl broadcast, ZERO inner syncs.
//   - Phase D: load diag as lower triangle + skew-reflect in LDS.
// A-access invariant: only entries i>j of the trailing matrix are maintained.
//
// Workspace layout:
//   0:    flags[256] (u32 epoch per block)
//   1024: logJ accumulator (double)
//   1088: nidx[1024] (int)
//   8192: tbuf / ybuf / hbuf0 / hbuf1 (4 x 64*2304 fp32)
//   2367488: A (1048*1048 fp64 = 8.79 MB)
// ---------------------------------------------------------------------------

#define NPIX 2304          // 48*48
#define MSZ  4608          // 2*48*48
#define NOCC 1024
#define NHID 24
#define PF_N 1048          // NOCC + 2*NHID
#define PF_BLOCKS 256

__device__ __forceinline__ float gelu_f(float v){
  // jax.nn.gelu approximate=True (tanh form)
  float v3 = v*v*v;
  return 0.5f*v*(1.0f + tanhf(0.7978845608028654f*(v + 0.044715f*v3)));
}

// coherent (cache-bypassing) A accessors: relaxed agent-scope atomics.
// Visible device-wide once vmcnt-acked; no fences needed (proven R5).
__device__ __forceinline__ double ald(const double* p){
  return __hip_atomic_load(p, __ATOMIC_RELAXED, __HIP_MEMORY_SCOPE_AGENT);
}
__device__ __forceinline__ void ast(double* p, double v){
  __hip_atomic_store(p, v, __ATOMIC_RELAXED, __HIP_MEMORY_SCOPE_AGENT);
}

// ---- occupied-site indices (sorted), x[i]==1.0f exactly ----
__global__ void k_find_n(const float* __restrict__ x, int* __restrict__ nidx){
  __shared__ int cnt[256];
  __shared__ int off[256];
  int t = threadIdx.x;
  int c = 0;
  for (int k = 0; k < 18; k++) c += (x[t*18+k] == 1.0f) ? 1 : 0;
  cnt[t] = c;
  __syncthreads();
  if (t == 0){ int s = 0; for (int q=0;q<256;q++){ off[q]=s; s+=cnt[q]; } }
  __syncthreads();
  int o = off[t];
  for (int k = 0; k < 18; k++){
    int idx = t*18+k;
    if (x[idx] == 1.0f) nidx[o++] = idx;
  }
}

// ---- elementwise pre-op: t = [gelu](h*scale) ----
__global__ void k_pre(const float* __restrict__ in, float* __restrict__ outp,
                      int count, int dogelu, float scale){
  int g = blockIdx.x*256 + threadIdx.x;
  if (g >= count) return;
  float v = in[g]*scale;
  if (dogelu) v = gelu_f(v);
  outp[g] = v;
}

// ---- circular 3x3 conv, 64 out channels, fused bias/gelu/residual/scale ----
__global__ __launch_bounds__(256) void k_conv(const float* __restrict__ in,
      const float* __restrict__ wgt, const float* __restrict__ bias,
      const float* __restrict__ res, float* __restrict__ outp,
      int cin, int resmode, int dogelu, float scale){
  int c = blockIdx.x / 9;
  int p = (blockIdx.x % 9)*256 + threadIdx.x;
  int y = p / 48, x = p - y*48;
  int ym = ((y+47)%48)*48, y0 = y*48, yp = ((y+1)%48)*48;
  int xm = (x+47)%48, xq = (x+1)%48;
  float s = 0.f;
  const float* wp = wgt + c*cin*9;
  for (int ci = 0; ci < cin; ci++){
    const float* b_ = in + ci*NPIX;
    s += b_[ym+xm]*wp[0] + b_[ym+x]*wp[1] + b_[ym+xq]*wp[2]
       + b_[y0+xm]*wp[3] + b_[y0+x]*wp[4] + b_[y0+xq]*wp[5]
       + b_[yp+xm]*wp[6] + b_[yp+x]*wp[7] + b_[yp+xq]*wp[8];
    wp += 9;
  }
  if (bias) s += bias[c];
  if (dogelu) s = gelu_f(s);
  if (resmode == 1) s += res[c*NPIX + p];
  else if (resmode == 2) s += res[(c>>5)*NPIX + p];  // jnp.repeat(res,32,axis=0)
  s *= scale;
  outp[c*NPIX + p] = s;
}

// ---- log_J = sum over channels 48..63 of final h ----
__global__ void k_logJ(const float* __restrict__ hfin, double* __restrict__ acc){
  int g = blockIdx.x*256 + threadIdx.x;   // 144*256 = 36864
  double v = (double)hfin[48*NPIX + g];
  for (int o = 32; o > 0; o >>= 1) v += __shfl_down(v, o, 64);
  __shared__ double wsum[4];
  int lane = threadIdx.x & 63, wv = threadIdx.x >> 6;
  if (lane == 0) wsum[wv] = v;
  __syncthreads();
  if (threadIdx.x == 0) atomicAdd(acc, wsum[0]+wsum[1]+wsum[2]+wsum[3]);
}

// F_vh[m][r] = out[2r + (m>=2304)][m % 2304]
__device__ __forceinline__ double fvh_val(const float* h, int m, int r){
  int s = (m >= NPIX) ? 1 : 0;
  int p = m - s*NPIX;
  return (double)h[(2*r+s)*NPIX + p];
}

// ---- assemble skew matrix A (fp64) ----
__global__ void k_buildA(const float* __restrict__ Fvv, const float* __restrict__ Fhh,
                         const float* __restrict__ hfin, const int* __restrict__ nidx,
                         double* __restrict__ A){
  int g = blockIdx.x*256 + threadIdx.x;
  if (g >= PF_N*PF_N) return;
  int i = g / PF_N, j = g - i*PF_N;
  double v;
  if (i < NOCC){
    int ni = nidx[i];
    if (j < NOCC){
      int nj = nidx[j];
      v = 0.5*((double)Fvv[(size_t)ni*MSZ + nj] - (double)Fvv[(size_t)nj*MSZ + ni]);
    } else {
      v = fvh_val(hfin, ni, j - NOCC);
    }
  } else {
    int r = i - NOCC;
    if (j < NOCC){
      v = -fvh_val(hfin, nidx[j], r);
    } else {
      int r2 = j - NOCC;
      v = 0.5*((double)Fhh[r*NHID + r2] - (double)Fhh[r2*NHID + r]);
    }
  }
  A[g] = v;
}

// ---- fence-free flag-array grid barrier (proven R5) ----
__device__ __forceinline__ void gridbar(unsigned* flags, unsigned ep){
  __syncthreads();                 // each wave: s_waitcnt vmcnt(0) + barrier
  const int tid = threadIdx.x;
  if (tid == 0){
    asm volatile("" ::: "memory");
    __builtin_amdgcn_s_waitcnt(0);
    __hip_atomic_store(&flags[blockIdx.x], ep, __ATOMIC_RELAXED,
                       __HIP_MEMORY_SCOPE_AGENT);
  }
  if (tid < 64){
    for (;;){
      unsigned v0 = __hip_atomic_load(&flags[tid      ], __ATOMIC_RELAXED, __HIP_MEMORY_SCOPE_AGENT);
      unsigned v1 = __hip_atomic_load(&flags[tid +  64], __ATOMIC_RELAXED, __HIP_MEMORY_SCOPE_AGENT);
      unsigned v2 = __hip_atomic_load(&flags[tid + 128], __ATOMIC_RELAXED, __HIP_MEMORY_SCOPE_AGENT);
      unsigned v3 = __hip_atomic_load(&flags[tid + 192], __ATOMIC_RELAXED, __HIP_MEMORY_SCOPE_AGENT);
      bool ok = (v0 >= ep) & (v1 >= ep) & (v2 >= ep) & (v3 >= ep);
      if (__all(ok)) break;
      __builtin_amdgcn_s_sleep(1);
    }
    asm volatile("" ::: "memory");
  }
  __syncthreads();
}

// ---- blocked skew LDL^T (2x2 pivots, panel=32 cols), Pf accumulation ----
// Invariant: only LOWER-triangle (i>j) trailing entries of A are maintained.
// Update rule (pivot step j, pivot rows r0=2j,r1=2j+1):
//   X[i][c] += (b_i*a_c - a_i*b_c)/t   with a_x = X[x][r0], b_x = X[x][r1]
__global__ __launch_bounds__(256) void k_pf(double* __restrict__ A,
      unsigned* __restrict__ flags, const double* __restrict__ logJ,
      float* __restrict__ outp){
  const int N = PF_N;
  const int tid = threadIdx.x;
  __shared__ double sBuf[4352];     // D[32][34] | T stages 4 x [64][17]
  __shared__ double sAA[16][32];    // a_c^{(j)} history
  __shared__ double sBB[16][32];    // b_c^{(j)} history
  __shared__ double sInv[16];
  __shared__ double sT[16];
  double lsum = 0.0, lsgn = 1.0;    // meaningful in block0/thread0
  unsigned ep = 0;

  for (int c0 = 0; c0 < N; c0 += 32){
    const int w  = (N - c0 < 32) ? (N - c0) : 32;
    const int np = w >> 1;

    // ---------------- phase D: redundant diagonal factorization ----------------
    {
      double* D = sBuf;  // [32][34]
      // load lower triangle, reflect upper via skew symmetry
      for (int idx = tid; idx < 32*32; idx += 256){
        int r = idx >> 5, c = idx & 31;
        double v = 0.0;
        if (r < w && c < w && r > c) v = ald(&A[(size_t)(c0+r)*N + c0 + c]);
        D[r*34+c] = v;
      }
      __syncthreads();
      for (int idx = tid; idx < 32*32; idx += 256){
        int r = idx >> 5, c = idx & 31;
        if (r < c && r < w && c < w) D[r*34+c] = -D[c*34+r];
      }
      __syncthreads();
      for (int j = 0; j < np; j++){
        const int r0 = 2*j, r1 = 2*j+1;
        const double t = D[r0*34+r1];
        const double invt = 1.0 / t;
        if (tid == 0){ sInv[j] = invt; sT[j] = t; }
        if (tid < 32){ sAA[j][tid] = D[tid*34+r0]; sBB[j][tid] = D[tid*34+r1]; }
        for (int idx = tid; idx < 32*32; idx += 256){
          int r = idx >> 5, c = idx & 31;
          if (r >= 2*j+2 && c >= 2*j+2 && r < w && c < w){
            double ar = D[r*34+r0], br = D[r*34+r1];
            double ac = D[c*34+r0], bc = D[c*34+r1];
            D[r*34+c] += (br*ac - ar*bc) * invt;
          }
        }
        __syncthreads();
      }
      // parallel pivot log/sign reduction (block 0 only)
      if (blockIdx.x == 0 && tid < 64){
        double lv = 0.0; int sg = 0;
        if (tid < np){ double t = sT[tid]; lv = log(fabs(t)); sg = (t < 0.0) ? 1 : 0; }
        for (int o = 8; o > 0; o >>= 1){
          lv += __shfl_down(lv, o, 64);
          sg += __shfl_down(sg, o, 64);
        }
        if (tid == 0){ lsum += lv; if (sg & 1) lsgn = -lsgn; }
      }
    }

    const int tc0 = c0 + w;
    const int m = N - tc0;

    // ---------------- phase R: panel cols of trailing rows, shfl-based --------
    // lane = 16*g + c within wave: row = i0 + (tid>>4), col pair (2c,2c+1)
    // in registers; 16 rank-2 steps with __shfl broadcast; ZERO syncs.
    if (m > 0){               // whenever m>0, w==32 and np==16
      const int nrt = (m + 15) >> 4;
      const int cc_ = tid & 15;
      for (int item = blockIdx.x; item < nrt; item += PF_BLOCKS){
        const int i = tc0 + item*16 + (tid >> 4);
        const bool ok = (i < N);
        double a = 0.0, b = 0.0;
        if (ok){
          a = ald(&A[(size_t)i*N + c0 + 2*cc_]);
          b = ald(&A[(size_t)i*N + c0 + 2*cc_ + 1]);
        }
        #pragma unroll
        for (int j = 0; j < 16; j++){
          double arj = __shfl(a, j, 16);
          double brj = __shfl(b, j, 16);
          if (cc_ > j){
            double invt = sInv[j];
            a += (brj*sAA[j][2*cc_  ] - arj*sBB[j][2*cc_  ]) * invt;
            b += (brj*sAA[j][2*cc_+1] - arj*sBB[j][2*cc_+1]) * invt;
          }
        }
        if (ok){
          ast(&A[(size_t)i*N + c0 + 2*cc_    ], a);
          ast(&A[(size_t)i*N + c0 + 2*cc_ + 1], b);
        }
      }
    }
    gridbar(flags, ++ep);

    // ---------------- phase T: trailing rank-32 update, lower triangle --------
    if (m > 0){
      double* sQr = sBuf;           // [64][17] a_i
      double* sPr = sBuf + 1088;    // [64][17] b_i * invt
      double* sQc = sBuf + 2176;    // [64][17] a_j
      double* sPc = sBuf + 3264;    // [64][17] b_j * invt
      const int nrt = (m + 63) >> 6;
      const int nitems = nrt*(nrt+1)/2;
      for (int item = blockIdx.x; item < nitems; item += PF_BLOCKS){
        int rt = 0;
        while ((rt+1)*(rt+2)/2 <= item) rt++;
        const int ct = item - rt*(rt+1)/2;
        const int i0 = tc0 + rt*64, j0 = tc0 + ct*64;
        const int iend = (i0 + 64 < N) ? (i0 + 64) : N;
        const int jend = (j0 + 64 < N) ? (j0 + 64) : N;
        // batched stage loads (rows then cols), all issued before first use
        #pragma unroll
        for (int u = 0; u < 4; u++){
          const int idx = tid + u*256;
          const int r = idx >> 4, l = idx & 15;
          const int i = i0 + r;
          double a = 0.0, b = 0.0;
          if (i < iend){
            a = ald(&A[(size_t)i*N + c0 + 2*l]);
            b = ald(&A[(size_t)i*N + c0 + 2*l + 1]);
          }
          sQr[r*17+l] = a;
          sPr[r*17+l] = b * sInv[l];
        }
        #pragma unroll
        for (int u = 0; u < 4; u++){
          const int idx = tid + u*256;
          const int r = idx >> 4, l = idx & 15;
          const int j = j0 + r;
          double a = 0.0, b = 0.0;
          if (j < jend){
            a = ald(&A[(size_t)j*N + c0 + 2*l]);
            b = ald(&A[(size_t)j*N + c0 + 2*l + 1]);
          }
          sQc[r*17+l] = a;
          sPc[r*17+l] = b * sInv[l];
        }
        __syncthreads();
        const int ty = tid >> 4, tx = tid & 15;
        const int ib = i0 + ty*4;
        #pragma unroll
        for (int cpass = 0; cpass < 2; cpass++){
          const int jb = j0 + tx*4 + cpass*2;
          double acc[4][2];
          #pragma unroll
          for (int rr = 0; rr < 4; rr++)
            #pragma unroll
            for (int cc = 0; cc < 2; cc++){
              const int i = ib+rr, jx = jb+cc;
              acc[rr][cc] = (i < iend && jx < jend && i > jx)
                          ? ald(&A[(size_t)i*N + jx]) : 0.0;
            }
          #pragma unroll
          for (int l = 0; l < 16; l++){
            double pr[4], qr[4], pc[2], qc[2];
            #pragma unroll
            for (int rr = 0; rr < 4; rr++){
              qr[rr] = sQr[(ty*4+rr)*17+l];
              pr[rr] = sPr[(ty*4+rr)*17+l];
            }
            #pragma unroll
            for (int cc = 0; cc < 2; cc++){
              qc[cc] = sQc[(tx*4+cpass*2+cc)*17+l];
              pc[cc] = sPc[(tx*4+cpass*2+cc)*17+l];
            }
            #pragma unroll
            for (int rr = 0; rr < 4; rr++)
              #pragma unroll
              for (int cc = 0; cc < 2; cc++)
                acc[rr][cc] += pr[rr]*qc[cc] - qr[rr]*pc[cc];
          }
          #pragma unroll
          for (int rr = 0; rr < 4; rr++)
            #pragma unroll
            for (int cc = 0; cc < 2; cc++){
              const int i = ib+rr, jx = jb+cc;
              if (i < iend && jx < jend && i > jx)
                ast(&A[(size_t)i*N + jx], acc[rr][cc]);
            }
        }
        __syncthreads();
      }
    }
    gridbar(flags, ++ep);
  }

  if (blockIdx.x == 0 && tid == 0){
    outp[0] = (float)lsgn;
    outp[1] = (float)(lsum + logJ[0]);
  }
}

// ---------------------------------------------------------------------------
extern "C" void kernel_launch(void* const* d_in, const int* in_sizes, int n_in,
                              void* d_out, int out_size, void* d_ws, size_t ws_size,
                              hipStream_t stream){
  (void)in_sizes; (void)n_in; (void)out_size; (void)ws_size;
  const float* x   = (const float*)d_in[0];
  const float* Fvv = (const float*)d_in[1];
  const float* Fhh = (const float*)d_in[2];
  const float* w1[4] = {(const float*)d_in[3], (const float*)d_in[7],
                        (const float*)d_in[11], (const float*)d_in[15]};
  const float* b1[4] = {(const float*)d_in[4], (const float*)d_in[8],
                        (const float*)d_in[12], (const float*)d_in[16]};
  const float* w2[4] = {(const float*)d_in[5], (const float*)d_in[9],
                        (const float*)d_in[13], (const float*)d_in[17]};
  const float* b2[3] = {(const float*)d_in[6], (const float*)d_in[10],
                        (const float*)d_in[14]};

  char* ws = (char*)d_ws;
  unsigned* flags = (unsigned*)(ws + 0);        // 256 x u32
  double* logJa  = (double*)(ws + 1024);
  int*    nidx   = (int*)(ws + 1088);
  const size_t CB = 589824;  // 64*2304*4
  float* tbuf  = (float*)(ws + 8192);
  float* ybuf  = (float*)(ws + 8192 + CB);
  float* hbuf0 = (float*)(ws + 8192 + 2*CB);
  float* hbuf1 = (float*)(ws + 8192 + 3*CB);
  double* A    = (double*)(ws + 8192 + 4*CB);   // offset 2367488, 8.79 MB

  hipMemsetAsync(d_ws, 0, 2048, stream);        // flags + logJ acc
  k_find_n<<<1,256,0,stream>>>(x, nidx);

  // CNN block 0: t = (h/sqrt(1))/sqrt(2); res repeats 2ch -> 64ch
  k_pre <<<18, 256,0,stream>>>(x, tbuf, 4608, 0, 0.70710678118654752f);
  k_conv<<<576,256,0,stream>>>(tbuf, w1[0], b1[0], nullptr, ybuf, 2, 0, 1, 1.0f);
  k_conv<<<576,256,0,stream>>>(ybuf, w2[0], b2[0], x,      hbuf0, 64, 2, 0, 1.0f);
  // block 1
  k_pre <<<576,256,0,stream>>>(hbuf0, tbuf, 147456, 1, 0.70710678118654752f);
  k_conv<<<576,256,0,stream>>>(tbuf, w1[1], b1[1], nullptr, ybuf, 64, 0, 1, 1.0f);
  k_conv<<<576,256,0,stream>>>(ybuf, w2[1], b2[1], hbuf0,  hbuf1, 64, 1, 0, 1.0f);
  // block 2
  k_pre <<<576,256,0,stream>>>(hbuf1, tbuf, 147456, 1, 0.57735026918962576f);
  k_conv<<<576,256,0,stream>>>(tbuf, w1[2], b1[2], nullptr, ybuf, 64, 0, 1, 1.0f);
  k_conv<<<576,256,0,stream>>>(ybuf, w2[2], b2[2], hbuf1,  hbuf0, 64, 1, 0, 1.0f);
  // block 3 (no b2; fold final 1/sqrt(5) into epilogue)
  k_pre <<<576,256,0,stream>>>(hbuf0, tbuf, 147456, 1, 0.5f);
  k_conv<<<576,256,0,stream>>>(tbuf, w1[3], b1[3], nullptr, ybuf, 64, 0, 1, 1.0f);
  k_conv<<<576,256,0,stream>>>(ybuf, w2[3], nullptr, hbuf0, hbuf1, 64, 1, 0,
                               0.44721359549995794f);

  k_logJ  <<<144,256,0,stream>>>(hbuf1, logJa);
  k_buildA<<<(PF_N*PF_N+255)/256,256,0,stream>>>(Fvv, Fhh, hbuf1, nidx, A);
  k_pf    <<<PF_BLOCKS,256,0,stream>>>(A, flags, logJa, (float*)d_out);
}

// Round 7
// 1422.938 us; speedup vs baseline: 1.1211x; 1.1211x over previous
//
#include <hip/hip_runtime.h>
#include <math.h>

// ---------------------------------------------------------------------------
// HFPS: CNN (4 residual blocks, circular 3x3 conv, 48x48, 64ch) ->
//       A = [[Fvv[n][:,n], Fvh_n],[-Fvh_n^T, Fhh_a]] (1048x1048 skew) ->
//       sign(Pf(A)), log|Pf(A)| + log_J
// Pfaffian via unpivoted blocked skew LDL^T with 2x2 pivots, fp64.
//   Pf = prod(t_p); log|Pf| = sum log|t_p| = 0.5*slogdet(A).
//
// R7: DISTRIBUTED-A design (R6 post-mortem: per-panel global round-trips of
// the whole trailing matrix through the bypass path are the invariant cost;
// tile-shape tweaks can't fix it):
//   - row i of A lives in LDS of block (i mod 256) for the whole kernel
//     (<=5 rows, <=21.4 KB). A is NEVER materialized in global memory;
//     each block gathers its rows directly from Fvv/Fhh/hfin (buildA gone).
//   - per panel k (BK=64): only two small cross-block surfaces:
//       Pk[m][64]  = panel columns after in-panel factorization (R phase)
//       Dk+1[64][64] = next diagonal tile
//     written via relaxed agent-scope atomic stores (bypass, proven R5),
//     read via NORMAL CACHED loads -- safe: each Pk/Dk is a fresh address
//     range first touched only after its barrier (no stale lines), and
//     dispatch-boundary cache invalidation covers graph replays.
//   - phase D: register-tile (4x4/thread) redundant factorization; pivot
//     columns broadcast through 1 KB LDS per step.
//   - 33 grid barriers total (fence-free flag barrier, proven R5).
//
// Workspace layout:
//   0:       flags[256] (u32 epoch per block)
//   1024:    logJ accumulator (double)
//   1088:    nidx[1024] (int)
//   8192:    tbuf / ybuf / hbuf0 / hbuf1 (4 x 64*2304 fp32)
//   2367488: Pk panel buffers (8064*64*8 = 4,128,768 B)
//   6496256: Dk diag buffers (17*64*64*8 = 557,056 B)
// ---------------------------------------------------------------------------

#define NPIX 2304          // 48*48
#define MSZ  4608          // 2*48*48
#define NOCC 1024
#define NHID 24
#define PF_N 1048          // NOCC + NHID
#define PF_BLOCKS 256
#define NPAN 17            // 16 panels of 64 + final 24

__device__ __forceinline__ float gelu_f(float v){
  // jax.nn.gelu approximate=True (tanh form)
  float v3 = v*v*v;
  return 0.5f*v*(1.0f + tanhf(0.7978845608028654f*(v + 0.044715f*v3)));
}

// coherent (cache-bypassing) accessors: relaxed agent-scope atomics (R5).
__device__ __forceinline__ double ald(const double* p){
  return __hip_atomic_load(p, __ATOMIC_RELAXED, __HIP_MEMORY_SCOPE_AGENT);
}
__device__ __forceinline__ void ast(double* p, double v){
  __hip_atomic_store(p, v, __ATOMIC_RELAXED, __HIP_MEMORY_SCOPE_AGENT);
}

// ---- occupied-site indices (sorted), x[i]==1.0f exactly ----
__global__ void k_find_n(const float* __restrict__ x, int* __restrict__ nidx){
  __shared__ int cnt[256];
  __shared__ int off[256];
  int t = threadIdx.x;
  int c = 0;
  for (int k = 0; k < 18; k++) c += (x[t*18+k] == 1.0f) ? 1 : 0;
  cnt[t] = c;
  __syncthreads();
  if (t == 0){ int s = 0; for (int q=0;q<256;q++){ off[q]=s; s+=cnt[q]; } }
  __syncthreads();
  int o = off[t];
  for (int k = 0; k < 18; k++){
    int idx = t*18+k;
    if (x[idx] == 1.0f) nidx[o++] = idx;
  }
}

// ---- elementwise pre-op: t = [gelu](h*scale) ----
__global__ void k_pre(const float* __restrict__ in, float* __restrict__ outp,
                      int count, int dogelu, float scale){
  int g = blockIdx.x*256 + threadIdx.x;
  if (g >= count) return;
  float v = in[g]*scale;
  if (dogelu) v = gelu_f(v);
  outp[g] = v;
}

// ---- circular 3x3 conv, 64 out channels, fused bias/gelu/residual/scale ----
__global__ __launch_bounds__(256) void k_conv(const float* __restrict__ in,
      const float* __restrict__ wgt, const float* __restrict__ bias,
      const float* __restrict__ res, float* __restrict__ outp,
      int cin, int resmode, int dogelu, float scale){
  int c = blockIdx.x / 9;
  int p = (blockIdx.x % 9)*256 + threadIdx.x;
  int y = p / 48, x = p - y*48;
  int ym = ((y+47)%48)*48, y0 = y*48, yp = ((y+1)%48)*48;
  int xm = (x+47)%48, xq = (x+1)%48;
  float s = 0.f;
  const float* wp = wgt + c*cin*9;
  for (int ci = 0; ci < cin; ci++){
    const float* b_ = in + ci*NPIX;
    s += b_[ym+xm]*wp[0] + b_[ym+x]*wp[1] + b_[ym+xq]*wp[2]
       + b_[y0+xm]*wp[3] + b_[y0+x]*wp[4] + b_[y0+xq]*wp[5]
       + b_[yp+xm]*wp[6] + b_[yp+x]*wp[7] + b_[yp+xq]*wp[8];
    wp += 9;
  }
  if (bias) s += bias[c];
  if (dogelu) s = gelu_f(s);
  if (resmode == 1) s += res[c*NPIX + p];
  else if (resmode == 2) s += res[(c>>5)*NPIX + p];  // jnp.repeat(res,32,axis=0)
  s *= scale;
  outp[c*NPIX + p] = s;
}

// ---- log_J = sum over channels 48..63 of final h ----
__global__ void k_logJ(const float* __restrict__ hfin, double* __restrict__ acc){
  int g = blockIdx.x*256 + threadIdx.x;   // 144*256 = 36864
  double v = (double)hfin[48*NPIX + g];
  for (int o = 32; o > 0; o >>= 1) v += __shfl_down(v, o, 64);
  __shared__ double wsum[4];
  int lane = threadIdx.x & 63, wv = threadIdx.x >> 6;
  if (lane == 0) wsum[wv] = v;
  __syncthreads();
  if (threadIdx.x == 0) atomicAdd(acc, wsum[0]+wsum[1]+wsum[2]+wsum[3]);
}

// ---- fence-free flag-array grid barrier (proven R5) ----
__device__ __forceinline__ void gridbar(unsigned* flags, unsigned ep){
  __syncthreads();                 // each wave: s_waitcnt vmcnt(0) + barrier
  const int tid = threadIdx.x;
  if (tid == 0){
    asm volatile("" ::: "memory");
    __builtin_amdgcn_s_waitcnt(0);
    __hip_atomic_store(&flags[blockIdx.x], ep, __ATOMIC_RELAXED,
                       __HIP_MEMORY_SCOPE_AGENT);
  }
  if (tid < 64){
    for (;;){
      unsigned v0 = __hip_atomic_load(&flags[tid      ], __ATOMIC_RELAXED, __HIP_MEMORY_SCOPE_AGENT);
      unsigned v1 = __hip_atomic_load(&flags[tid +  64], __ATOMIC_RELAXED, __HIP_MEMORY_SCOPE_AGENT);
      unsigned v2 = __hip_atomic_load(&flags[tid + 128], __ATOMIC_RELAXED, __HIP_MEMORY_SCOPE_AGENT);
      unsigned v3 = __hip_atomic_load(&flags[tid + 192], __ATOMIC_RELAXED, __HIP_MEMORY_SCOPE_AGENT);
      bool ok = (v0 >= ep) & (v1 >= ep) & (v2 >= ep) & (v3 >= ep);
      if (__all(ok)) break;
      __builtin_amdgcn_s_sleep(1);
    }
    asm volatile("" ::: "memory");
  }
  __syncthreads();
}

// Pk offset in doubles: 64 * sum_{k'<k} (984 - 64k')
__device__ __forceinline__ size_t pk_off(int k){
  return (size_t)64 * ((size_t)984*(size_t)k - (size_t)32*(size_t)k*(size_t)(k-1));
}

// ---- distributed-A blocked skew LDL^T (2x2 pivots, BK=64) ----
// Block b owns rows {b, b+256, b+512, b+768} (+ b+1024 if b<24) in LDS.
// rI(s) = b+256s ; row s storage offset roff(s) = s*b + 128*s*(s-1).
__global__ __launch_bounds__(256) void k_pf(
      const float* __restrict__ Fvv, const float* __restrict__ Fhh,
      const float* __restrict__ hfin, const int* __restrict__ nidx_g,
      double* __restrict__ Pbase, double* __restrict__ Dbase,
      unsigned* __restrict__ flags, const double* __restrict__ logJ,
      float* __restrict__ outp){
  const int N = PF_N;
  const int tid = threadIdx.x;
  const int b = blockIdx.x;
  const int nrows = (b < 24) ? 5 : 4;

  __shared__ double rowbuf[2688];   // owned rows, cols 0..i-1 packed
  __shared__ double sAAf[32][64];   // Dt[c][2j]  * invt_j  (history)
  __shared__ double sBBf[32][64];   // Dt[c][2j+1]* invt_j
  __shared__ double colA[64], colB[64];
  __shared__ double sInv[32], sTv[32];
  __shared__ double sCA[5][32], sCB[5][32];
  __shared__ int    snidx[1024];

  #define RIDX(s)  (b + 256*(s))
  #define ROFF(s)  ((s)*b + 128*(s)*((s)-1))

  for (int q = tid; q < 1024; q += 256) snidx[q] = nidx_g[q];
  __syncthreads();

  // ---- gather own rows straight from inputs (no global A) ----
  for (int s = 0; s < nrows; s++){
    const int i = RIDX(s);
    const int o = ROFF(s);
    if (i < NOCC){
      const int ni = snidx[i];
      const float* rowF = Fvv + (size_t)ni*MSZ;
      for (int j = tid; j < i; j += 256){
        int nj = snidx[j];
        rowbuf[o+j] = 0.5*((double)rowF[nj] - (double)Fvv[(size_t)nj*MSZ + ni]);
      }
    } else {
      const int r = i - NOCC;
      for (int j = tid; j < i; j += 256){
        double v;
        if (j < NOCC){
          int nj = snidx[j];
          int ss = (nj >= NPIX) ? 1 : 0;
          v = -(double)hfin[(2*r+ss)*NPIX + (nj - ss*NPIX)];
        } else {
          int r2 = j - NOCC;
          v = 0.5*((double)Fhh[r*NHID+r2] - (double)Fhh[r2*NHID+r]);
        }
        rowbuf[o+j] = v;
      }
    }
  }
  __syncthreads();

  // ---- publish diag tile 0 (rows 0..63; owner blocks 0..63, s=0) ----
  if (b < 64){
    for (int c = tid; c < b; c += 256)
      ast(&Dbase[(size_t)b*64 + c], rowbuf[c]);
  }
  unsigned ep = 0;
  gridbar(flags, ++ep);

  double lsum = 0.0, lsgn = 1.0;   // block 0 / thread 0

  for (int k = 0; k < NPAN; k++){
    const int c0  = 64*k;
    const int w   = (N - c0 < 64) ? (N - c0) : 64;
    const int np  = w >> 1;
    const int tc0 = c0 + w;
    const int m   = N - tc0;
    const double* Dk = Dbase + (size_t)k*4096;
    double* Pk = (m > 0) ? (Pbase + pk_off(k)) : (double*)0;

    // ---------------- phase D: register-tile redundant factorization --------
    {
      const int ty = tid >> 4, tx = tid & 15;   // 16x16 threads of 4x4 tiles
      double T4[4][4];
      #pragma unroll
      for (int q = 0; q < 4; q++)
        #pragma unroll
        for (int p = 0; p < 4; p++){
          int r = 4*ty+q, c = 4*tx+p;
          double v = 0.0;
          if (r < w && c < w){
            if (r > c) v = Dk[r*64+c];
            else if (r < c) v = -Dk[c*64+r];
          }
          T4[q][p] = v;
        }
      for (int j = 0; j < np; j++){
        const int r0 = 2*j, r1 = 2*j+1;
        if (tx == (r0 >> 2)){
          const bool lo = ((r0 & 3) == 0);
          #pragma unroll
          for (int q = 0; q < 4; q++){
            colA[4*ty+q] = lo ? T4[q][0] : T4[q][2];
            colB[4*ty+q] = lo ? T4[q][1] : T4[q][3];
          }
        }
        __syncthreads();
        const double t = colB[r0];
        const double invt = 1.0 / t;
        if (tid == 0){ sInv[j] = invt; sTv[j] = t; }
        if (tid < 64){
          sAAf[j][tid] = colA[tid]*invt;
          sBBf[j][tid] = colB[tid]*invt;
        }
        #pragma unroll
        for (int q = 0; q < 4; q++){
          const int r = 4*ty+q;
          const double ar = colA[r], br = colB[r];
          #pragma unroll
          for (int p = 0; p < 4; p++){
            const int c = 4*tx+p;
            if (r >= 2*j+2 && c >= 2*j+2)
              T4[q][p] += (br*colA[c] - ar*colB[c])*invt;
          }
        }
        __syncthreads();
      }
      if (b == 0 && tid < 64){
        double lv = 0.0; int sg = 0;
        if (tid < np){ double t = sTv[tid]; lv = log(fabs(t)); sg = (t<0.0)?1:0; }
        for (int o = 32; o > 0; o >>= 1){
          lv += __shfl_down(lv, o, 64);
          sg += __shfl_down(sg, o, 64);
        }
        if (tid == 0){ lsum += lv; if (sg & 1) lsgn = -lsgn; }
      }
    }

    // ---------------- phase R: own trailing rows' panel cols (local) --------
    if (m > 0){               // m>0 implies w==64, np==32
      const int wv = tid >> 6, lc = tid & 63;
      for (int s = wv; s < nrows; s += 4){
        const int i = RIDX(s);
        if (i < tc0) continue;
        const int o = ROFF(s);
        double v = rowbuf[o + c0 + lc];
        #pragma unroll 8
        for (int j = 0; j < 32; j++){
          double a  = __shfl(v, 2*j,   64);
          double bb = __shfl(v, 2*j+1, 64);
          if (lc >= 2*j+2) v += bb*sAAf[j][lc] - a*sBBf[j][lc];
        }
        rowbuf[o + c0 + lc] = v;
        ast(&Pk[(size_t)(i - tc0)*64 + lc], v);
      }
      __syncthreads();
      // T coefficients: sCB = b_i*invt (x a_j), sCA = a_i*invt (x b_j)
      {
        const int s = tid >> 5, l = tid & 31;
        if (s < nrows && tid < 160){
          const int i = RIDX(s);
          if (i >= tc0){
            const int o = ROFF(s);
            sCA[s][l] = rowbuf[o + c0 + 2*l    ] * sInv[l];
            sCB[s][l] = rowbuf[o + c0 + 2*l + 1] * sInv[l];
          }
        }
      }
    }
    gridbar(flags, ++ep);

    // ---------------- phase T: rank-64 update of own rows (LDS-resident) ----
    if (m > 0){
      const int maxOwn = RIDX(nrows-1);
      for (int base = tc0; base < maxOwn; base += 256){
        const int j = base + tid;
        const bool jv = (j < maxOwn);
        double acc[5];
        #pragma unroll
        for (int s = 0; s < 5; s++){
          acc[s] = 0.0;
          if (s < nrows && jv && j < RIDX(s)) acc[s] = rowbuf[ROFF(s) + j];
        }
        if (jv){
          const double* pr = Pk + (size_t)(j - tc0)*64;  // normal cached reads
          #pragma unroll 4
          for (int l = 0; l < 32; l++){
            double a  = pr[2*l];
            double bb = pr[2*l+1];
            #pragma unroll
            for (int s = 0; s < 5; s++)
              acc[s] += sCB[s][l]*a - sCA[s][l]*bb;
          }
          #pragma unroll
          for (int s = 0; s < 5; s++)
            if (s < nrows && j < RIDX(s)) rowbuf[ROFF(s) + j] = acc[s];
        }
      }
      __syncthreads();
      // publish next diag tile: rows in [tc0, tc0+64)
      for (int s = 0; s < nrows; s++){
        const int i = RIDX(s);
        if (i >= tc0 && i < tc0 + 64){
          double* Dn = Dbase + (size_t)(k+1)*4096 + (size_t)(i - tc0)*64;
          const int o = ROFF(s);
          for (int c = tid; c < i - tc0; c += 256)
            ast(&Dn[c], rowbuf[o + tc0 + c]);
        }
      }
    }
    gridbar(flags, ++ep);
  }

  if (b == 0 && tid == 0){
    outp[0] = (float)lsgn;
    outp[1] = (float)(lsum + logJ[0]);
  }
  #undef RIDX
  #undef ROFF
}

// ---------------------------------------------------------------------------
extern "C" void kernel_launch(void* const* d_in, const int* in_sizes, int n_in,
                              void* d_out, int out_size, void* d_ws, size_t ws_size,
                              hipStream_t stream){
  (void)in_sizes; (void)n_in; (void)out_size; (void)ws_size;
  const float* x   = (const float*)d_in[0];
  const float* Fvv = (const float*)d_in[1];
  const float* Fhh = (const float*)d_in[2];
  const float* w1[4] = {(const float*)d_in[3], (const float*)d_in[7],
                        (const float*)d_in[11], (const float*)d_in[15]};
  const float* b1[4] = {(const float*)d_in[4], (const float*)d_in[8],
                        (const float*)d_in[12], (const float*)d_in[16]};
  const float* w2[4] = {(const float*)d_in[5], (const float*)d_in[9],
                        (const float*)d_in[13], (const float*)d_in[17]};
  const float* b2[3] = {(const float*)d_in[6], (const float*)d_in[10],
                        (const float*)d_in[14]};

  char* ws = (char*)d_ws;
  unsigned* flags = (unsigned*)(ws + 0);        // 256 x u32
  double* logJa  = (double*)(ws + 1024);
  int*    nidx   = (int*)(ws + 1088);
  const size_t CB = 589824;  // 64*2304*4
  float* tbuf  = (float*)(ws + 8192);
  float* ybuf  = (float*)(ws + 8192 + CB);
  float* hbuf0 = (float*)(ws + 8192 + 2*CB);
  float* hbuf1 = (float*)(ws + 8192 + 3*CB);
  double* Pbase = (double*)(ws + 8192 + 4*CB);            // 2,367,488
  double* Dbase = (double*)(ws + 8192 + 4*CB + 4128768);  // 6,496,256

  hipMemsetAsync(d_ws, 0, 2048, stream);        // flags + logJ acc
  k_find_n<<<1,256,0,stream>>>(x, nidx);

  // CNN block 0: t = (h/sqrt(1))/sqrt(2); res repeats 2ch -> 64ch
  k_pre <<<18, 256,0,stream>>>(x, tbuf, 4608, 0, 0.70710678118654752f);
  k_conv<<<576,256,0,stream>>>(tbuf, w1[0], b1[0], nullptr, ybuf, 2, 0, 1, 1.0f);
  k_conv<<<576,256,0,stream>>>(ybuf, w2[0], b2[0], x,      hbuf0, 64, 2, 0, 1.0f);
  // block 1
  k_pre <<<576,256,0,stream>>>(hbuf0, tbuf, 147456, 1, 0.70710678118654752f);
  k_conv<<<576,256,0,stream>>>(tbuf, w1[1], b1[1], nullptr, ybuf, 64, 0, 1, 1.0f);
  k_conv<<<576,256,0,stream>>>(ybuf, w2[1], b2[1], hbuf0,  hbuf1, 64, 1, 0, 1.0f);
  // block 2
  k_pre <<<576,256,0,stream>>>(hbuf1, tbuf, 147456, 1, 0.57735026918962576f);
  k_conv<<<576,256,0,stream>>>(tbuf, w1[2], b1[2], nullptr, ybuf, 64, 0, 1, 1.0f);
  k_conv<<<576,256,0,stream>>>(ybuf, w2[2], b2[2], hbuf1,  hbuf0, 64, 1, 0, 1.0f);
  // block 3 (no b2; fold final 1/sqrt(5) into epilogue)
  k_pre <<<576,256,0,stream>>>(hbuf0, tbuf, 147456, 1, 0.5f);
  k_conv<<<576,256,0,stream>>>(tbuf, w1[3], b1[3], nullptr, ybuf, 64, 0, 1, 1.0f);
  k_conv<<<576,256,0,stream>>>(ybuf, w2[3], nullptr, hbuf0, hbuf1, 64, 1, 0,
                               0.44721359549995794f);

  k_logJ<<<144,256,0,stream>>>(hbuf1, logJa);
  k_pf  <<<PF_BLOCKS,256,0,stream>>>(Fvv, Fhh, hbuf1, nidx,
                                     Pbase, Dbase, flags, logJa, (float*)d_out);
}